// Round 2
// 876.728 us; speedup vs baseline: 1.1007x; 1.1007x over previous
//
#include <hip/hip_runtime.h>
#include <hip/hip_bf16.h>

// ---------------------------------------------------------------------------
// Sparse 3-level U-Net — Round 19: counted-vmcnt pipeline, FIXED prologue.
// R18 failed (absmax 5.47): prologue VMEM ops (idx loads + stage0..2 +
// gather0..2) were one unordered scheduling region; scheduler could issue
// global_load_lds last, so vmcnt(16) left stage(k) in flight -> stale LDS.
// global_load_lds has no dest VGPR, so the compiler inserts NO automatic
// waits for it — manual counting must be made sound:
//   (a) sched_barrier(0) + memory clobber pins every STAGE/LOADA region,
//   (b) one-time s_waitcnt vmcnt(0) before the k-loop (buffers 0,1 certain),
//   (c) in-loop counted vmcnt(2*(SG+GA)) — never drains to 0 in steady state.
// Baseline R17: 965 us (y1 gmfma 102 us, MfmaUtil 12.5%).
// ---------------------------------------------------------------------------

typedef __hip_bfloat16 hbf;
typedef __attribute__((ext_vector_type(8))) short short8;
typedef __attribute__((ext_vector_type(4))) float f32x4;
typedef const __attribute__((address_space(1))) short gas_short;
typedef __attribute__((address_space(3))) short las_short;

__device__ inline float b2f(short s) {
    unsigned u = ((unsigned)(unsigned short)s) << 16;
    float f; __builtin_memcpy(&f, &u, 4); return f;
}
__device__ inline short f2b(float f) {
    hbf h = __float2bfloat16(f);
    short s; __builtin_memcpy(&s, &h, 2); return s;
}

// ---------- weight prep: f32 [K][CI][CO] -> bf16 FRAGMENT-MAJOR ------------
// wf[(((k*NCH + c)*NT + t)*64 + lane)*8 + j] = w[k][c*32+(lane>>4)*8+j][t*16+(lane&15)]
__global__ void wprep2(const float* __restrict__ w, short* __restrict__ wf,
                       int K, int CI, int CO) {
    int total = K * CI * CO;
    int e = blockIdx.x * blockDim.x + threadIdx.x;
    if (e >= total) return;
    int NT = CO / 16, NCH = CI / 32;
    int j    = e & 7;
    int lane = (e >> 3) & 63;
    int t    = (e >> 9) % NT;
    int c    = (e / (512 * NT)) % NCH;
    int k    = e / (512 * NT * NCH);
    int ci = c * 32 + (lane >> 4) * 8 + j;
    int co = t * 16 + (lane & 15);
    wf[e] = f2b(w[((long long)k * CI + ci) * CO + co]);
}

// ---------- input conv (CIN=3, f32 VALU, bf16 out) -------------------------
__global__ __launch_bounds__(256) void conv_in(
    const float* __restrict__ feat, const int* __restrict__ nbr,
    const float* __restrict__ W, short* __restrict__ out, int N) {
    __shared__ float sW[27 * 96];
    const int tid = threadIdx.x;
    for (int e = tid; e < 27 * 96; e += 256) sW[e] = W[e];
    __syncthreads();
    long long r = (long long)blockIdx.x * 256 + tid;
    if (r >= N) return;
    float acc[32];
#pragma unroll
    for (int c = 0; c < 32; c++) acc[c] = 0.f;
    for (int k = 0; k < 27; k++) {
        int idx = nbr[r * 27 + k];
        if (idx >= 0) {
            float f0 = feat[(long long)idx * 3];
            float f1 = feat[(long long)idx * 3 + 1];
            float f2 = feat[(long long)idx * 3 + 2];
            const float* w = sW + k * 96;
#pragma unroll
            for (int c = 0; c < 32; c++)
                acc[c] += f0 * w[c] + f1 * w[32 + c] + f2 * w[64 + c];
        }
    }
#pragma unroll
    for (int c = 0; c < 32; c++) out[r * 32 + c] = f2b(acc[c]);
}

// ---------- MFMA gather conv v5: 4-buf ring, sound counted-vmcnt -----------
template<int CI1, int CI2, int COUT, int K>
__global__ __launch_bounds__(256) void gmfma5(
    const short* __restrict__ fA, const short* __restrict__ fB,
    const int* __restrict__ nbr, const short* __restrict__ Wf,
    short* __restrict__ out, int N) {
    constexpr int CITOT = CI1 + CI2;
    constexpr int NT  = COUT / 16;
    constexpr int NC1 = CI1 / 32;
    constexpr int NC2 = CI2 / 32;
    constexpr int NCH = CITOT / 32;
    constexpr int PANEL  = NCH * NT * 512;            // shorts per k-panel
    constexpr int CHUNKS = PANEL / 4;                 // shorts per wave
    constexpr int N16 = (CHUNKS * 2) / 1024;          // 1KB (16B/lane) calls
    constexpr int N4  = ((CHUNKS * 2) % 1024) / 256;  // 256B (4B/lane) calls
    constexpr int SG  = N16 + N4;                     // stage ops / wave / k
    constexpr int GA  = NCH;                          // gather ops / wave / k
    constexpr int NWAIT = 2 * (SG + GA);              // keep 2 iters in flight
    __shared__ __attribute__((aligned(16))) short sB[4][PANEL];
    const int tid  = threadIdx.x;
    const int lane = tid & 63;
    const int wid  = tid >> 6;
    const int m    = lane & 15;
    const int quad = lane >> 4;
    const long long row0 = ((long long)blockIdx.x * 4 + wid) * 16;
    const long long r = row0 + m;
    const bool rv = r < N;

    f32x4 acc[NT];
#pragma unroll
    for (int t = 0; t < NT; t++) acc[t] = (f32x4)0.f;

    int idxs[K];
#pragma unroll
    for (int k = 0; k < K; k++) idxs[k] = rv ? nbr[r * K + k] : -1;

    short8 abuf[3][NCH];

    // Unconditional gather (clamp + select) -> constant vmcnt op count.
#define LOADA(kk, bb)                                                          \
    {                                                                          \
        int _i = idxs[kk];                                                     \
        long long _j = _i < 0 ? 0 : _i;                                        \
        _Pragma("unroll")                                                      \
        for (int c = 0; c < NC1; c++) {                                        \
            short8 _v = *reinterpret_cast<const short8*>(                      \
                fA + _j * CI1 + c * 32 + quad * 8);                            \
            abuf[bb][c] = (_i >= 0) ? _v : (short8)0;                          \
        }                                                                      \
        if constexpr (NC2 > 0) {                                               \
            _Pragma("unroll")                                                  \
            for (int c = 0; c < NC2; c++) {                                    \
                short8 _v = *reinterpret_cast<const short8*>(                  \
                    fB + _j * CI2 + c * 32 + quad * 8);                        \
                abuf[bb][NC1 + c] = (_i >= 0) ? _v : (short8)0;                \
            }                                                                  \
        }                                                                      \
    }
    // Direct global->LDS staging; each wave stages its quarter of the panel.
#define STAGE(kk, bb)                                                          \
    {                                                                          \
        const short* _src = Wf + (size_t)(kk) * PANEL + wid * CHUNKS;          \
        short* _dst = &sB[bb][wid * CHUNKS];                                   \
        _Pragma("unroll")                                                      \
        for (int i = 0; i < N16; i++)                                          \
            __builtin_amdgcn_global_load_lds(                                  \
                (gas_short*)(_src + i * 512 + lane * 8),                       \
                (las_short*)(_dst + i * 512), 16, 0, 0);                       \
        _Pragma("unroll")                                                      \
        for (int i = 0; i < N4; i++)                                           \
            __builtin_amdgcn_global_load_lds(                                  \
                (gas_short*)(_src + N16 * 512 + i * 128 + lane * 2),           \
                (las_short*)(_dst + N16 * 512 + i * 128), 4, 0, 0);            \
    }
#define FENCE()                                                                \
    __builtin_amdgcn_sched_barrier(0);                                         \
    asm volatile("" ::: "memory");

    STAGE(0, 0)
    LOADA(0, 0)
    FENCE()
    STAGE(1, 1)
    LOADA(1, 1)
    FENCE()
    // One-time drain: buffers 0,1 certainly staged regardless of scheduling.
    // global_load_lds has no dest VGPR -> compiler will NOT protect it.
    asm volatile("s_waitcnt vmcnt(0)" ::: "memory");
    __builtin_amdgcn_sched_barrier(0);
#pragma unroll
    for (int k = 0; k < K; k++) {
        // distance-2 prefetch; wrap at the tail to keep counts constant
        int kk = (k + 2 < K) ? (k + 2) : (k + 2 - K);
        STAGE(kk, (k + 2) & 3)
        LOADA(kk, (k + 2) % 3)
        FENCE()
        // my stage(k)+gather(k) retired; <=2 iterations stay in flight
        asm volatile("s_waitcnt vmcnt(%0)" :: "n"(NWAIT) : "memory");
        __builtin_amdgcn_s_barrier();          // all waves' stage(k) done
        FENCE()
#pragma unroll
        for (int c = 0; c < NCH; c++) {
#pragma unroll
            for (int t = 0; t < NT; t++) {
                short8 b = *reinterpret_cast<const short8*>(
                    &sB[k & 3][((c * NT + t) * 64 + lane) * 8]);
                acc[t] = __builtin_amdgcn_mfma_f32_16x16x32_bf16(
                    abuf[k % 3][c], b, acc[t], 0, 0, 0);
            }
        }
    }
#undef LOADA
#undef STAGE
#undef FENCE
    // D: col = lane&15, row = quad*4 + reg
#pragma unroll
    for (int g = 0; g < 4; g++) {
        long long sr = row0 + quad * 4 + g;
        if (sr < N) {
#pragma unroll
            for (int t = 0; t < NT; t++)
                out[sr * COUT + t * 16 + m] = f2b(acc[t][g]);
        }
    }
}

// ---------- MFMA transposed (up) conv v5: 4-buf ring pipeline --------------
template<int CIN, int COUT>
__global__ __launch_bounds__(256) void upmfma5(
    const short* __restrict__ f, const int* __restrict__ rb,
    const short* __restrict__ Wf, short* __restrict__ out, int N) {
    constexpr int NT = COUT / 16;
    constexpr int NK = CIN / 32;
    constexpr int PANEL  = NK * NT * 512;
    constexpr int CHUNKS = PANEL / 4;
    constexpr int N16 = (CHUNKS * 2) / 1024;
    constexpr int N4  = ((CHUNKS * 2) % 1024) / 256;
    constexpr int SG  = N16 + N4;
    constexpr int NWAIT = 2 * SG;   // stores in flight only make this stricter
    __shared__ __attribute__((aligned(16))) short sB[4][PANEL];
    const int tid  = threadIdx.x;
    const int lane = tid & 63;
    const int wid  = tid >> 6;
    const int m    = lane & 15;
    const int quad = lane >> 4;
    const long long row0 = ((long long)blockIdx.x * 4 + wid) * 16;
    const long long r = row0 + m;
    const bool rv = r < N;
    const long long rc = rv ? r : 0;

    short8 af[NK];
#pragma unroll
    for (int kc = 0; kc < NK; kc++) {
        short8 v = *reinterpret_cast<const short8*>(
            f + rc * CIN + kc * 32 + quad * 8);
        af[kc] = rv ? v : (short8)0;
    }
    int sidx[8][4];
#pragma unroll
    for (int g = 0; g < 4; g++) {
        long long sr = row0 + quad * 4 + g;
#pragma unroll
        for (int k = 0; k < 8; k++)
            sidx[k][g] = (sr < N) ? rb[sr * 8 + k] : -1;
    }
#define STAGE(kk, bb)                                                          \
    {                                                                          \
        const short* _src = Wf + (size_t)(kk) * PANEL + wid * CHUNKS;          \
        short* _dst = &sB[bb][wid * CHUNKS];                                   \
        _Pragma("unroll")                                                      \
        for (int i = 0; i < N16; i++)                                          \
            __builtin_amdgcn_global_load_lds(                                  \
                (gas_short*)(_src + i * 512 + lane * 8),                       \
                (las_short*)(_dst + i * 512), 16, 0, 0);                       \
        _Pragma("unroll")                                                      \
        for (int i = 0; i < N4; i++)                                           \
            __builtin_amdgcn_global_load_lds(                                  \
                (gas_short*)(_src + N16 * 512 + i * 128 + lane * 2),           \
                (las_short*)(_dst + N16 * 512 + i * 128), 4, 0, 0);            \
    }
#define FENCE()                                                                \
    __builtin_amdgcn_sched_barrier(0);                                         \
    asm volatile("" ::: "memory");

    STAGE(0, 0)
    FENCE()
    STAGE(1, 1)
    FENCE()
    asm volatile("s_waitcnt vmcnt(0)" ::: "memory");
    __builtin_amdgcn_sched_barrier(0);
#pragma unroll
    for (int k = 0; k < 8; k++) {
        int kk = (k + 2 < 8) ? (k + 2) : (k + 2 - 8);
        STAGE(kk, (k + 2) & 3)
        FENCE()
        asm volatile("s_waitcnt vmcnt(%0)" :: "n"(NWAIT) : "memory");
        __builtin_amdgcn_s_barrier();
        FENCE()
        f32x4 acc[NT];
#pragma unroll
        for (int t = 0; t < NT; t++) acc[t] = (f32x4)0.f;
#pragma unroll
        for (int kc = 0; kc < NK; kc++) {
#pragma unroll
            for (int t = 0; t < NT; t++) {
                short8 b = *reinterpret_cast<const short8*>(
                    &sB[k & 3][((kc * NT + t) * 64 + lane) * 8]);
                acc[t] = __builtin_amdgcn_mfma_f32_16x16x32_bf16(af[kc], b, acc[t], 0, 0, 0);
            }
        }
#pragma unroll
        for (int g = 0; g < 4; g++) {
            if (sidx[k][g] >= 0) {
#pragma unroll
                for (int t = 0; t < NT; t++)
                    out[(long long)sidx[k][g] * COUT + t * 16 + m] = f2b(acc[t][g]);
            }
        }
    }
#undef STAGE
#undef FENCE
}

// ---------- BN stats: short8 coalesced loads, f64 deterministic ------------
template<int C>
__global__ void bn_stats(const short* __restrict__ x, double* __restrict__ part, int N) {
    constexpr int GR  = C / 8;
    constexpr int RPB = 256 / GR;
    constexpr int ACTIVE = GR * RPB;
    __shared__ double ls[256 * 8];
    __shared__ double lq[256 * 8];
    const int tid = threadIdx.x;
    const int g   = tid % GR;
    const int rr  = tid / GR;
    double s[8], q[8];
#pragma unroll
    for (int j = 0; j < 8; j++) { s[j] = 0.0; q[j] = 0.0; }
    if (tid < ACTIVE) {
        for (long long r = (long long)blockIdx.x * RPB + rr; r < N;
             r += (long long)gridDim.x * RPB) {
            short8 v = *reinterpret_cast<const short8*>(x + r * C + g * 8);
#pragma unroll
            for (int j = 0; j < 8; j++) {
                double f = (double)b2f(v[j]);
                s[j] += f; q[j] += f * f;
            }
        }
    }
#pragma unroll
    for (int j = 0; j < 8; j++) { ls[tid * 8 + j] = s[j]; lq[tid * 8 + j] = q[j]; }
    __syncthreads();
    if (tid < C) {
        int gg = tid / 8, jj = tid % 8;
        double S = 0.0, Q = 0.0;
        for (int r2 = 0; r2 < RPB; r2++) {
            S += ls[(r2 * GR + gg) * 8 + jj];
            Q += lq[(r2 * GR + gg) * 8 + jj];
        }
        part[blockIdx.x * 256 + tid]       = S;
        part[blockIdx.x * 256 + 128 + tid] = Q;
    }
}

__global__ void bn_fin(const double* __restrict__ part, const float* __restrict__ gb,
                       int gbfull, int goff, float* __restrict__ ab,
                       int C, int P, double invN) {
    __shared__ double ss[256], sq[256];
    const int tid = threadIdx.x;
    const int c   = tid % C;
    const int g   = tid / C;
    const int G   = 256 / C;
    double s = 0.0, q = 0.0;
    if (g < G) {
        for (int p = g; p < P; p += G) {
            s += part[p * 256 + c];
            q += part[p * 256 + 128 + c];
        }
    }
    ss[tid] = s; sq[tid] = q;
    __syncthreads();
    if (tid < C) {
        for (int j = 1; j < G; j++) { s += ss[j * C + c]; q += sq[j * C + c]; }
        double mu  = s * invN;
        double var = q * invN - mu * mu;
        double a   = (double)gb[goff + c] / sqrt(var + 1e-4);
        ab[c]     = (float)a;
        ab[C + c] = (float)((double)gb[gbfull + goff + c] - mu * a);
    }
}

// ---------- bnact: y = relu(x*a + b), bf16 -> bf16, 8 elems/thread ---------
template<int C>
__global__ void bnact(const short* __restrict__ x, const float* __restrict__ ab,
                      short* __restrict__ y, long long total8) {
    long long i = (long long)blockIdx.x * blockDim.x + threadIdx.x;
    if (i >= total8) return;
    long long base = i * 8;
    int c0 = (int)(base % C);
    short8 v = *reinterpret_cast<const short8*>(x + base);
    short8 o;
#pragma unroll
    for (int j = 0; j < 8; j++) {
        float f = b2f(v[j]) * ab[c0 + j] + ab[C + c0 + j];
        o[j] = f2b(f > 0.f ? f : 0.f);
    }
    *reinterpret_cast<short8*>(y + base) = o;
}

// ---------- final linear (bnf fused), bf16 in, f32 out ---------------------
__global__ void final_k(const short* __restrict__ x, const float* __restrict__ ab,
                        const float* __restrict__ lw, const float* __restrict__ lb,
                        float* __restrict__ out, int N) {
    long long r = (long long)blockIdx.x * blockDim.x + threadIdx.x;
    if (r >= N) return;
    float a0 = lb[0], a1 = lb[1];
#pragma unroll
    for (int j = 0; j < 4; j++) {
        short8 v = *reinterpret_cast<const short8*>(x + r * 32 + j * 8);
#pragma unroll
        for (int t = 0; t < 8; t++) {
            int ci = 8 * j + t;
            float u = b2f(v[t]) * ab[ci] + ab[32 + ci];
            u = u > 0.f ? u : 0.f;
            a0 += u * lw[ci * 2];
            a1 += u * lw[ci * 2 + 1];
        }
    }
    out[2 * r]     = a0;
    out[2 * r + 1] = a1;
}

extern "C" void kernel_launch(void* const* d_in, const int* in_sizes, int n_in,
                              void* d_out, int out_size, void* d_ws, size_t ws_size,
                              hipStream_t stream) {
    const long long N0 = in_sizes[0] / 3;
    const long long N1 = in_sizes[26] / 8;
    const long long N2 = in_sizes[27] / 8;
    const int P = 256;

    const float* feat = (const float*)d_in[0];
    const int* nbr0 = (const int*)d_in[23];
    const int* nbr1 = (const int*)d_in[24];
    const int* nbr2 = (const int*)d_in[25];
    const int* rb0  = (const int*)d_in[26];
    const int* rb1  = (const int*)d_in[27];

    // ---- arena ----
    char* p = (char*)d_ws;
    double* part = (double*)p;            p += (size_t)P * 256 * 8;     // 512 KB
    float*  ab   = (float*)p;             p += 12 * 256 * 4;
    const int wLayer[9] = {3, 5, 7, 9, 11, 13, 15, 17, 19};
    const int wK[9]  = {27, 8, 27, 8, 27, 8, 27, 8, 27};
    const int wCI[9] = {32, 32, 64, 64, 96, 96, 128, 64, 64};
    const int wCO[9] = {32, 64, 64, 96, 96, 64, 64, 32, 32};
    short* wt[9];
    for (int i = 0; i < 9; i++) {
        wt[i] = (short*)p;
        size_t n = (size_t)wK[i] * wCI[i] * wCO[i];
        p += ((n * 2 + 63) & ~(size_t)63);
    }
    auto balloc = [&](long long elems) {
        short* q = (short*)p;
        p += (((size_t)elems * 2 + 63) & ~(size_t)63);
        return q;
    };
    short* R0 = balloc(N0 * 32);   // t0 / d0 / d1 / u1 / u0 (raw)
    short* R1 = balloc(N0 * 32);   // x0 raw (persist)
    short* R2 = balloc(N1 * 64);   // x1 raw (persist)
    short* R3 = balloc(N0 * 32);   // x2 / y1 / y0 (raw)
    short* Xb = balloc(N0 * 32);   // bnact out #1
    short* Yb = balloc(N0 * 32);   // bnact out #2

    for (int i = 0; i < 9; i++) {
        int n = wK[i] * wCI[i] * wCO[i];
        wprep2<<<(n + 255) / 256, 256, 0, stream>>>(
            (const float*)d_in[wLayer[i]], wt[i], wK[i], wCI[i], wCO[i]);
    }

#define STATS(CH, X, NN) bn_stats<CH><<<P, 256, 0, stream>>>(X, part, (int)(NN))
#define FIN(GBI, GBFULL, GOFF, SL, CH, NN)                                           \
    bn_fin<<<1, 256, 0, stream>>>(part, (const float*)d_in[GBI], GBFULL, GOFF,       \
                                  ab + (SL) * 256, CH, P, 1.0 / (double)(NN))
#define AB(SL) (ab + (SL) * 256)
#define ACT(CH, X, SL, Y, NN)                                                        \
    bnact<CH><<<(int)(((NN) * (CH) / 8 + 255) / 256), 256, 0, stream>>>(             \
        X, AB(SL), Y, (NN) * (CH) / 8)
#define GB(N_) (int)(((N_) + 63) / 64)

    // ---- level 0 ----
    conv_in<<<(int)((N0 + 255) / 256), 256, 0, stream>>>(
        feat, nbr0, (const float*)d_in[1], R0, (int)N0);                  // t0 -> R0
    STATS(32, R0, N0); FIN(2, 32, 0, 0, 32, N0); ACT(32, R0, 0, Xb, N0);  // bn1_0
    gmfma5<32, 0, 32, 27><<<GB(N0), 256, 0, stream>>>(
        Xb, nullptr, nbr0, wt[0], R1, (int)N0);                           // x0 -> R1
    STATS(32, R1, N0); FIN(4, 32, 0, 1, 32, N0); ACT(32, R1, 1, Xb, N0);  // bnd_0
    gmfma5<32, 0, 64, 8><<<GB(N1), 256, 0, stream>>>(
        Xb, nullptr, rb0, wt[1], R0, (int)N1);                            // d0 -> R0

    // ---- level 1 ----
    STATS(64, R0, N1); FIN(6, 64, 0, 2, 64, N1); ACT(64, R0, 2, Xb, N1);  // bn1_1
    gmfma5<64, 0, 64, 27><<<GB(N1), 256, 0, stream>>>(
        Xb, nullptr, nbr1, wt[2], R2, (int)N1);                           // x1 -> R2
    STATS(64, R2, N1); FIN(8, 64, 0, 3, 64, N1); ACT(64, R2, 3, Xb, N1);  // bnd_1
    gmfma5<64, 0, 96, 8><<<GB(N2), 256, 0, stream>>>(
        Xb, nullptr, rb1, wt[3], R0, (int)N2);                            // d1 -> R0

    // ---- level 2 ----
    STATS(96, R0, N2); FIN(10, 96, 0, 4, 96, N2); ACT(96, R0, 4, Xb, N2); // bn1_2
    gmfma5<96, 0, 96, 27><<<GB(N2), 256, 0, stream>>>(
        Xb, nullptr, nbr2, wt[4], R3, (int)N2);                           // x2 -> R3
    STATS(96, R3, N2); FIN(12, 96, 0, 5, 96, N2); ACT(96, R3, 5, Xb, N2); // bnu_1

    // ---- up to level 1 ----
    upmfma5<96, 64><<<GB(N2), 256, 0, stream>>>(
        Xb, rb1, wt[5], R0, (int)N2);                                     // u1 -> R0
    STATS(64, R2, N1); FIN(14, 128, 0, 6, 64, N1);                        // bn2_1 [x1]
    STATS(64, R0, N1); FIN(14, 128, 64, 7, 64, N1);                       // bn2_1 [u1]
    ACT(64, R2, 6, Xb, N1); ACT(64, R0, 7, Yb, N1);
    gmfma5<64, 64, 64, 27><<<GB(N1), 256, 0, stream>>>(
        Xb, Yb, nbr1, wt[6], R3, (int)N1);                                // y1 -> R3
    STATS(64, R3, N1); FIN(16, 64, 0, 8, 64, N1); ACT(64, R3, 8, Xb, N1); // bnu_0

    // ---- up to level 0 ----
    upmfma5<64, 32><<<GB(N1), 256, 0, stream>>>(
        Xb, rb0, wt[7], R0, (int)N1);                                     // u0 -> R0
    STATS(32, R1, N0); FIN(18, 64, 0, 9, 32, N0);                         // bn2_0 [x0]
    STATS(32, R0, N0); FIN(18, 64, 32, 10, 32, N0);                       // bn2_0 [u0]
    ACT(32, R1, 9, Xb, N0); ACT(32, R0, 10, Yb, N0);
    gmfma5<32, 32, 32, 27><<<GB(N0), 256, 0, stream>>>(
        Xb, Yb, nbr0, wt[8], R3, (int)N0);                                // y0 -> R3
    STATS(32, R3, N0); FIN(20, 32, 0, 11, 32, N0);                        // bnf

    final_k<<<(int)((N0 + 255) / 256), 256, 0, stream>>>(
        R3, AB(11), (const float*)d_in[21], (const float*)d_in[22],
        (float*)d_out, (int)N0);

#undef STATS
#undef FIN
#undef AB
#undef ACT
#undef GB
}